// Round 21
// baseline (90.954 us; speedup 1.0000x reference)
//
#include <hip/hip_runtime.h>
#include <hip/hip_bf16.h>
#include <cstdint>

// EdgeMLP R19 = R18 (validated i8 path, absmax 1.66e-2) with:
//   - main: 32-edge tiles, depth-2 pipeline. i8 transient epilogue keeps the
//     ledger ~106 VGPR (no persistent acc - that's what killed bf16 32-edge).
//     W1 LDS fragments shared by both 16-edge sub-tiles (0.5 ds_read/edge).
//   - prep: hmax grid 384 -> 2048 (was 1.5 blocks/CU for a BW-bound reduce).
// ws: [hq: nNodes*64 i8][swbits u32][hmbits u32][w1q 16K i8][w2tab 2048 bf16]

constexpr int EMB = 64;
constexpr int HID = 128;

typedef int   i32x4 __attribute__((ext_vector_type(4)));
typedef short s16x8 __attribute__((ext_vector_type(8)));
typedef float f32x4 __attribute__((ext_vector_type(4)));

__device__ __forceinline__ unsigned short f2bf(float x) {
    unsigned u = __float_as_uint(x);
    u = (u + 0x7fffu + ((u >> 16) & 1u)) >> 16;   // RNE
    return (unsigned short)u;
}

// ---- prep A1: global max|W1| (64 atomics total) ----
__global__ void w1max_kernel(const float* __restrict__ W1, unsigned* __restrict__ swbits) {
    const int i = blockIdx.x * 256 + threadIdx.x;   // grid 16
    float4 v = *reinterpret_cast<const float4*>(W1 + (size_t)i * 4);
    float m = fmaxf(fmaxf(fabsf(v.x), fabsf(v.y)), fmaxf(fabsf(v.z), fabsf(v.w)));
    #pragma unroll
    for (int off = 1; off < 64; off <<= 1) m = fmaxf(m, __shfl_xor(m, off, 64));
    if ((threadIdx.x & 63) == 0) atomicMax(swbits, __float_as_uint(m));
}

// ---- prep A2: global max|h| — grid-stride, ONE atomic per block ----
__global__ void hmax_kernel(const float* __restrict__ h, unsigned* __restrict__ hmbits,
                            int n4) {
    __shared__ float red[4];
    float m = 0.f;
    for (int i = blockIdx.x * blockDim.x + threadIdx.x; i < n4;
         i += gridDim.x * blockDim.x) {
        float4 v = *reinterpret_cast<const float4*>(h + (size_t)i * 4);
        m = fmaxf(m, fmaxf(fmaxf(fabsf(v.x), fabsf(v.y)), fmaxf(fabsf(v.z), fabsf(v.w))));
    }
    #pragma unroll
    for (int off = 1; off < 64; off <<= 1) m = fmaxf(m, __shfl_xor(m, off, 64));
    if ((threadIdx.x & 63) == 0) red[threadIdx.x >> 6] = m;
    __syncthreads();
    if (threadIdx.x == 0)
        atomicMax(hmbits, __float_as_uint(
            fmaxf(fmaxf(red[0], red[1]), fmaxf(red[2], red[3]))));
}

// ---- prep B: quantize h with the global scale (16 f32/thread) ----
__global__ void quant_h_g(const float* __restrict__ h, const unsigned* __restrict__ hmb,
                          char* __restrict__ hq, int n16) {
    const int i = blockIdx.x * blockDim.x + threadIdx.x;
    if (i >= n16) return;
    const float inv = 127.f / fmaxf(__uint_as_float(hmb[0]), 1e-18f);
    const float* p = h + (size_t)i * 16;
    unsigned w[4];
    #pragma unroll
    for (int q = 0; q < 4; ++q) {
        float4 v = *reinterpret_cast<const float4*>(p + q * 4);
        int a = max(-127, min(127, __float2int_rn(v.x * inv)));
        int b = max(-127, min(127, __float2int_rn(v.y * inv)));
        int c = max(-127, min(127, __float2int_rn(v.z * inv)));
        int d = max(-127, min(127, __float2int_rn(v.w * inv)));
        w[q] = (a & 255) | ((b & 255) << 8) | ((c & 255) << 16) | ((unsigned)(d & 255) << 24);
    }
    *reinterpret_cast<uint4*>(hq + (size_t)i * 16) = make_uint4(w[0], w[1], w[2], w[3]);
}

// ---- prep C: W1 i8 fragments + W2 bf16 fragments (validated layouts) ----
__global__ void pack_tabs_i8(const float* __restrict__ W1, const float* __restrict__ W2,
                             const unsigned* __restrict__ swb,
                             char* __restrict__ w1q, unsigned short* __restrict__ w2t) {
    const int i = blockIdx.x * blockDim.x + threadIdx.x;
    if (i < 16384) {
        const int j = i & 15, lane = (i >> 4) & 63, half = (i >> 10) & 1, mt = i >> 11;
        const int k = half * 64 + (lane >> 4) * 16 + j;
        const int n = mt * 16 + (lane & 15);
        const float inv = 127.f / fmaxf(__uint_as_float(swb[0]), 1e-18f);
        w1q[i] = (char)max(-127, min(127, __float2int_rn(W1[(size_t)k * HID + n] * inv)));
    } else if (i < 16384 + 2048) {
        const int q = i - 16384;
        const int j = q & 7, lane = (q >> 3) & 63, ks = q >> 9;
        const int tc = lane & 15, bq = lane >> 4;
        const int mt = ks * 2 + (j >> 2), r = j & 3;
        w2t[q] = (tc < 2) ? f2bf(W2[(mt * 16 + bq * 4 + r) * 2 + tc]) : (unsigned short)0;
    }
}

// ---- main: 32-edge tiles, depth-2, shared W1 fragment reads ----
__global__ __launch_bounds__(256, 2)
void edge_mlp_i8v5(const char* __restrict__ hq,
                   const unsigned* __restrict__ swb,
                   const unsigned* __restrict__ hmb,
                   const char* __restrict__ w1q,
                   const unsigned short* __restrict__ w2t,
                   const int* __restrict__ eidx,
                   const float* __restrict__ b1,
                   const float* __restrict__ b2,
                   float* __restrict__ out, int E, int nTiles32)
{
    __shared__ uint4 w1s[1024];   // 16 KB i8 W1 fragments
    __shared__ uint4 w2s[256];    // 4 KB  W2 bf16 fragments
    __shared__ float b1s[128];    // 512 B
    {
        const uint4* src = reinterpret_cast<const uint4*>(w1q);
        #pragma unroll
        for (int r = 0; r < 4; ++r)
            w1s[r * 256 + threadIdx.x] = src[r * 256 + threadIdx.x];
        w2s[threadIdx.x] = *(reinterpret_cast<const uint4*>(w2t) + threadIdx.x);
        if (threadIdx.x < 128) b1s[threadIdx.x] = b1[threadIdx.x];
    }
    __syncthreads();

    const float sTot = __uint_as_float(hmb[0]) * __uint_as_float(swb[0])
                       * (1.0f / (127.f * 127.f));

    const int t = threadIdx.x, wid = t >> 6, lane = t & 63;
    const int tc = lane & 15, bq = lane >> 4;
    const i32x4* wq  = reinterpret_cast<const i32x4*>(w1s) + lane;  // + (mt*2+half)*64
    const s16x8* wf2 = reinterpret_cast<const s16x8*>(w2s) + lane;  // + ks2*64
    const float* b1v = b1s + bq * 4;                                // + mt*16

    const float a20 = (bq == 0) ? b2[0] : 0.f;
    const float a21 = (bq == 0) ? b2[1] : 0.f;

    const int stride = gridDim.x * 4;
    int tile = blockIdx.x * 4 + wid;
    if (tile >= nTiles32) return;

    auto LOADIDX = [&](int tl, int& sA, int& dA, int& sB, int& dB) {
        if (tl < nTiles32) {
            const int base = tl * 32;
            const int eA = min(base + tc, E - 1);
            const int eB = min(base + 16 + tc, E - 1);
            sA = eidx[eA]; dA = eidx[E + eA];
            sB = eidx[eB]; dB = eidx[E + eB];
        } else { sA = 0; dA = 0; sB = 0; dB = 0; }
    };
    auto GATHER = [&](int sA, int dA, int sB, int dB,
                      i32x4& xSA, i32x4& xDA, i32x4& xSB, i32x4& xDB) {
        xSA = *reinterpret_cast<const i32x4*>(hq + (size_t)sA * EMB + bq * 16);
        xDA = *reinterpret_cast<const i32x4*>(hq + (size_t)dA * EMB + bq * 16);
        xSB = *reinterpret_cast<const i32x4*>(hq + (size_t)sB * EMB + bq * 16);
        xDB = *reinterpret_cast<const i32x4*>(hq + (size_t)dB * EMB + bq * 16);
    };
    auto COMPUTE = [&](int tl, i32x4 xSA, i32x4 xDA, i32x4 xSB, i32x4 xDB) {
        const i32x4 z = {0, 0, 0, 0};
        f32x4 oA = {a20, a21, 0.f, 0.f};
        f32x4 oB = {a20, a21, 0.f, 0.f};
        #pragma unroll
        for (int ks2 = 0; ks2 < 4; ++ks2) {
            s16x8 pA, pB;
            #pragma unroll
            for (int half = 0; half < 2; ++half) {
                const int mt = ks2 * 2 + half;
                const i32x4 f0 = wq[(mt * 2 + 0) * 64];   // shared by A and B
                const i32x4 f1 = wq[(mt * 2 + 1) * 64];
                const f32x4 bb = *reinterpret_cast<const f32x4*>(b1v + mt * 16);
                i32x4 accA = __builtin_amdgcn_mfma_i32_16x16x64_i8(f1, xDA, z, 0, 0, 0);
                accA = __builtin_amdgcn_mfma_i32_16x16x64_i8(f0, xSA, accA, 0, 0, 0);
                i32x4 accB = __builtin_amdgcn_mfma_i32_16x16x64_i8(f1, xDB, z, 0, 0, 0);
                accB = __builtin_amdgcn_mfma_i32_16x16x64_i8(f0, xSB, accB, 0, 0, 0);
                #pragma unroll
                for (int pr = 0; pr < 2; ++pr) {
                    const int r = pr * 2;
                    float hA0 = fmaxf(fmaf((float)accA[r],     sTot, bb[r]),     0.f);
                    float hA1 = fmaxf(fmaf((float)accA[r + 1], sTot, bb[r + 1]), 0.f);
                    __hip_bfloat162 pkA = __float22bfloat162_rn(make_float2(hA0, hA1));
                    reinterpret_cast<unsigned*>(&pA)[half * 2 + pr] = *reinterpret_cast<unsigned*>(&pkA);
                    float hB0 = fmaxf(fmaf((float)accB[r],     sTot, bb[r]),     0.f);
                    float hB1 = fmaxf(fmaf((float)accB[r + 1], sTot, bb[r + 1]), 0.f);
                    __hip_bfloat162 pkB = __float22bfloat162_rn(make_float2(hB0, hB1));
                    reinterpret_cast<unsigned*>(&pB)[half * 2 + pr] = *reinterpret_cast<unsigned*>(&pkB);
                }
            }
            const s16x8 w2r = wf2[ks2 * 64];   // shared by A and B
            oA = __builtin_amdgcn_mfma_f32_16x16x32_bf16(w2r, pA, oA, 0, 0, 0);
            oB = __builtin_amdgcn_mfma_f32_16x16x32_bf16(w2r, pB, oB, 0, 0, 0);
        }
        if (lane < 16) {
            const int eoA = tl * 32 + lane;
            if (eoA < E)
                *reinterpret_cast<float2*>(out + (size_t)eoA * 2) = make_float2(oA[0], oA[1]);
            const int eoB = eoA + 16;
            if (eoB < E)
                *reinterpret_cast<float2*>(out + (size_t)eoB * 2) = make_float2(oB[0], oB[1]);
        }
    };

    // ---- depth-2 pipeline, statically-named sets, no in-loop barrier ----
    int sA0, dA0, sB0, dB0, sA1, dA1, sB1, dB1;
    i32x4 xSA0, xDA0, xSB0, xDB0, xSA1, xDA1, xSB1, xDB1;

    LOADIDX(tile, sA0, dA0, sB0, dB0);
    GATHER(sA0, dA0, sB0, dB0, xSA0, xDA0, xSB0, xDB0);
    LOADIDX(tile + stride, sA1, dA1, sB1, dB1);

    while (true) {
        GATHER(sA1, dA1, sB1, dB1, xSA1, xDA1, xSB1, xDB1);
        LOADIDX(tile + 2 * stride, sA0, dA0, sB0, dB0);
        COMPUTE(tile, xSA0, xDA0, xSB0, xDB0);
        tile += stride;
        if (tile >= nTiles32) break;

        GATHER(sA0, dA0, sB0, dB0, xSA0, xDA0, xSB0, xDB0);
        LOADIDX(tile + 2 * stride, sA1, dA1, sB1, dB1);
        COMPUTE(tile, xSA1, xDA1, xSB1, xDB1);
        tile += stride;
        if (tile >= nTiles32) break;
    }
}

// ---- fallback (ws too small; correct but slow) ----
__global__ void edge_mlp_naive(const float* __restrict__ h, const int* __restrict__ eidx,
                               const float* __restrict__ W1, const float* __restrict__ b1,
                               const float* __restrict__ W2, const float* __restrict__ b2,
                               float* __restrict__ out, int E) {
    const int e = blockIdx.x * 256 + threadIdx.x;
    if (e >= E) return;
    const float* hs = h + (size_t)eidx[e] * EMB;
    const float* hd = h + (size_t)eidx[E + e] * EMB;
    float o0 = b2[0], o1 = b2[1];
    for (int j = 0; j < HID; ++j) {
        float a = b1[j];
        for (int k = 0; k < EMB; ++k)
            a += hs[k] * W1[(size_t)k * HID + j] + hd[k] * W1[(size_t)(k + EMB) * HID + j];
        a = fmaxf(a, 0.f);
        o0 = fmaf(a, W2[j * 2 + 0], o0);
        o1 = fmaf(a, W2[j * 2 + 1], o1);
    }
    out[(size_t)e * 2 + 0] = o0;
    out[(size_t)e * 2 + 1] = o1;
}

extern "C" void kernel_launch(void* const* d_in, const int* in_sizes, int n_in,
                              void* d_out, int out_size, void* d_ws, size_t ws_size,
                              hipStream_t stream)
{
    const float* h  = (const float*)d_in[0];
    const int*   ei = (const int*)d_in[1];
    const float* W1 = (const float*)d_in[2];
    const float* b1 = (const float*)d_in[3];
    const float* W2 = (const float*)d_in[4];
    const float* b2 = (const float*)d_in[5];
    float* out = (float*)d_out;

    const int nNodes   = in_sizes[0] / EMB;
    const int E        = in_sizes[1] / 2;
    const int nTiles32 = (E + 31) / 32;
    const int total    = nNodes * EMB;

    const size_t hq_off = 0;
    const size_t sw_off = (size_t)total;
    const size_t hm_off = sw_off + 4;
    const size_t w1_off = (hm_off + 4 + 15) & ~(size_t)15;
    const size_t w2_off = w1_off + 16384;
    const size_t need   = w2_off + 2048 * 2;

    if (ws_size >= need) {
        char*  ws  = (char*)d_ws;
        char*  hq  = ws + hq_off;
        unsigned* swb = (unsigned*)(ws + sw_off);
        unsigned* hmb = (unsigned*)(ws + hm_off);
        char*  w1q = ws + w1_off;
        unsigned short* w2t = (unsigned short*)(ws + w2_off);

        hipMemsetAsync(swb, 0, 8, stream);   // clears swb and hmb
        hipLaunchKernelGGL(w1max_kernel, dim3(16), dim3(256), 0, stream, W1, swb);
        hipLaunchKernelGGL(hmax_kernel, dim3(2048), dim3(256), 0, stream,
                           h, hmb, total / 4);
        hipLaunchKernelGGL(quant_h_g, dim3((total / 16 + 255) / 256), dim3(256), 0,
                           stream, h, hmb, hq, total / 16);
        hipLaunchKernelGGL(pack_tabs_i8, dim3(72), dim3(256), 0, stream,
                           W1, W2, swb, w1q, w2t);
        hipLaunchKernelGGL(edge_mlp_i8v5, dim3(1792), dim3(256), 0, stream,
                           hq, swb, hmb, w1q, w2t, ei, b1, b2, out, E, nTiles32);
    } else {
        hipLaunchKernelGGL(edge_mlp_naive, dim3((E + 255) / 256), dim3(256), 0, stream,
                           h, ei, W1, b1, W2, b2, out, E);
    }
}

// Round 22
// 90.746 us; speedup vs baseline: 1.0023x; 1.0023x over previous
//
#include <hip/hip_runtime.h>
#include <hip/hip_bf16.h>
#include <cstdint>

// EdgeMLP R19 = R18 (validated i8 path, absmax 1.66e-2) with:
//   - main: 32-edge tiles, depth-2 pipeline. i8 transient epilogue keeps the
//     ledger ~106 VGPR (no persistent acc - that's what killed bf16 32-edge).
//     W1 LDS fragments shared by both 16-edge sub-tiles (0.5 ds_read/edge).
//   - prep: hmax grid 384 -> 2048 (was 1.5 blocks/CU for a BW-bound reduce).
// ws: [hq: nNodes*64 i8][swbits u32][hmbits u32][w1q 16K i8][w2tab 2048 bf16]

constexpr int EMB = 64;
constexpr int HID = 128;

typedef int   i32x4 __attribute__((ext_vector_type(4)));
typedef short s16x8 __attribute__((ext_vector_type(8)));
typedef float f32x4 __attribute__((ext_vector_type(4)));

__device__ __forceinline__ unsigned short f2bf(float x) {
    unsigned u = __float_as_uint(x);
    u = (u + 0x7fffu + ((u >> 16) & 1u)) >> 16;   // RNE
    return (unsigned short)u;
}

// ---- prep A1: global max|W1| (64 atomics total) ----
__global__ void w1max_kernel(const float* __restrict__ W1, unsigned* __restrict__ swbits) {
    const int i = blockIdx.x * 256 + threadIdx.x;   // grid 16
    float4 v = *reinterpret_cast<const float4*>(W1 + (size_t)i * 4);
    float m = fmaxf(fmaxf(fabsf(v.x), fabsf(v.y)), fmaxf(fabsf(v.z), fabsf(v.w)));
    #pragma unroll
    for (int off = 1; off < 64; off <<= 1) m = fmaxf(m, __shfl_xor(m, off, 64));
    if ((threadIdx.x & 63) == 0) atomicMax(swbits, __float_as_uint(m));
}

// ---- prep A2: global max|h| — grid-stride, ONE atomic per block ----
__global__ void hmax_kernel(const float* __restrict__ h, unsigned* __restrict__ hmbits,
                            int n4) {
    __shared__ float red[4];
    float m = 0.f;
    for (int i = blockIdx.x * blockDim.x + threadIdx.x; i < n4;
         i += gridDim.x * blockDim.x) {
        float4 v = *reinterpret_cast<const float4*>(h + (size_t)i * 4);
        m = fmaxf(m, fmaxf(fmaxf(fabsf(v.x), fabsf(v.y)), fmaxf(fabsf(v.z), fabsf(v.w))));
    }
    #pragma unroll
    for (int off = 1; off < 64; off <<= 1) m = fmaxf(m, __shfl_xor(m, off, 64));
    if ((threadIdx.x & 63) == 0) red[threadIdx.x >> 6] = m;
    __syncthreads();
    if (threadIdx.x == 0)
        atomicMax(hmbits, __float_as_uint(
            fmaxf(fmaxf(red[0], red[1]), fmaxf(red[2], red[3]))));
}

// ---- prep B: quantize h with the global scale (16 f32/thread) ----
__global__ void quant_h_g(const float* __restrict__ h, const unsigned* __restrict__ hmb,
                          char* __restrict__ hq, int n16) {
    const int i = blockIdx.x * blockDim.x + threadIdx.x;
    if (i >= n16) return;
    const float inv = 127.f / fmaxf(__uint_as_float(hmb[0]), 1e-18f);
    const float* p = h + (size_t)i * 16;
    unsigned w[4];
    #pragma unroll
    for (int q = 0; q < 4; ++q) {
        float4 v = *reinterpret_cast<const float4*>(p + q * 4);
        int a = max(-127, min(127, __float2int_rn(v.x * inv)));
        int b = max(-127, min(127, __float2int_rn(v.y * inv)));
        int c = max(-127, min(127, __float2int_rn(v.z * inv)));
        int d = max(-127, min(127, __float2int_rn(v.w * inv)));
        w[q] = (a & 255) | ((b & 255) << 8) | ((c & 255) << 16) | ((unsigned)(d & 255) << 24);
    }
    *reinterpret_cast<uint4*>(hq + (size_t)i * 16) = make_uint4(w[0], w[1], w[2], w[3]);
}

// ---- prep C: W1 i8 fragments + W2 bf16 fragments (validated layouts) ----
__global__ void pack_tabs_i8(const float* __restrict__ W1, const float* __restrict__ W2,
                             const unsigned* __restrict__ swb,
                             char* __restrict__ w1q, unsigned short* __restrict__ w2t) {
    const int i = blockIdx.x * blockDim.x + threadIdx.x;
    if (i < 16384) {
        const int j = i & 15, lane = (i >> 4) & 63, half = (i >> 10) & 1, mt = i >> 11;
        const int k = half * 64 + (lane >> 4) * 16 + j;
        const int n = mt * 16 + (lane & 15);
        const float inv = 127.f / fmaxf(__uint_as_float(swb[0]), 1e-18f);
        w1q[i] = (char)max(-127, min(127, __float2int_rn(W1[(size_t)k * HID + n] * inv)));
    } else if (i < 16384 + 2048) {
        const int q = i - 16384;
        const int j = q & 7, lane = (q >> 3) & 63, ks = q >> 9;
        const int tc = lane & 15, bq = lane >> 4;
        const int mt = ks * 2 + (j >> 2), r = j & 3;
        w2t[q] = (tc < 2) ? f2bf(W2[(mt * 16 + bq * 4 + r) * 2 + tc]) : (unsigned short)0;
    }
}

// ---- main: 32-edge tiles, depth-2, shared W1 fragment reads ----
__global__ __launch_bounds__(256, 2)
void edge_mlp_i8v5(const char* __restrict__ hq,
                   const unsigned* __restrict__ swb,
                   const unsigned* __restrict__ hmb,
                   const char* __restrict__ w1q,
                   const unsigned short* __restrict__ w2t,
                   const int* __restrict__ eidx,
                   const float* __restrict__ b1,
                   const float* __restrict__ b2,
                   float* __restrict__ out, int E, int nTiles32)
{
    __shared__ uint4 w1s[1024];   // 16 KB i8 W1 fragments
    __shared__ uint4 w2s[256];    // 4 KB  W2 bf16 fragments
    __shared__ float b1s[128];    // 512 B
    {
        const uint4* src = reinterpret_cast<const uint4*>(w1q);
        #pragma unroll
        for (int r = 0; r < 4; ++r)
            w1s[r * 256 + threadIdx.x] = src[r * 256 + threadIdx.x];
        w2s[threadIdx.x] = *(reinterpret_cast<const uint4*>(w2t) + threadIdx.x);
        if (threadIdx.x < 128) b1s[threadIdx.x] = b1[threadIdx.x];
    }
    __syncthreads();

    const float sTot = __uint_as_float(hmb[0]) * __uint_as_float(swb[0])
                       * (1.0f / (127.f * 127.f));

    const int t = threadIdx.x, wid = t >> 6, lane = t & 63;
    const int tc = lane & 15, bq = lane >> 4;
    const i32x4* wq  = reinterpret_cast<const i32x4*>(w1s) + lane;  // + (mt*2+half)*64
    const s16x8* wf2 = reinterpret_cast<const s16x8*>(w2s) + lane;  // + ks2*64
    const float* b1v = b1s + bq * 4;                                // + mt*16

    const float a20 = (bq == 0) ? b2[0] : 0.f;
    const float a21 = (bq == 0) ? b2[1] : 0.f;

    const int stride = gridDim.x * 4;
    int tile = blockIdx.x * 4 + wid;
    if (tile >= nTiles32) return;

    auto LOADIDX = [&](int tl, int& sA, int& dA, int& sB, int& dB) {
        if (tl < nTiles32) {
            const int base = tl * 32;
            const int eA = min(base + tc, E - 1);
            const int eB = min(base + 16 + tc, E - 1);
            sA = eidx[eA]; dA = eidx[E + eA];
            sB = eidx[eB]; dB = eidx[E + eB];
        } else { sA = 0; dA = 0; sB = 0; dB = 0; }
    };
    auto GATHER = [&](int sA, int dA, int sB, int dB,
                      i32x4& xSA, i32x4& xDA, i32x4& xSB, i32x4& xDB) {
        xSA = *reinterpret_cast<const i32x4*>(hq + (size_t)sA * EMB + bq * 16);
        xDA = *reinterpret_cast<const i32x4*>(hq + (size_t)dA * EMB + bq * 16);
        xSB = *reinterpret_cast<const i32x4*>(hq + (size_t)sB * EMB + bq * 16);
        xDB = *reinterpret_cast<const i32x4*>(hq + (size_t)dB * EMB + bq * 16);
    };
    auto COMPUTE = [&](int tl, i32x4 xSA, i32x4 xDA, i32x4 xSB, i32x4 xDB) {
        const i32x4 z = {0, 0, 0, 0};
        f32x4 oA = {a20, a21, 0.f, 0.f};
        f32x4 oB = {a20, a21, 0.f, 0.f};
        #pragma unroll
        for (int ks2 = 0; ks2 < 4; ++ks2) {
            s16x8 pA, pB;
            #pragma unroll
            for (int half = 0; half < 2; ++half) {
                const int mt = ks2 * 2 + half;
                const i32x4 f0 = wq[(mt * 2 + 0) * 64];   // shared by A and B
                const i32x4 f1 = wq[(mt * 2 + 1) * 64];
                const f32x4 bb = *reinterpret_cast<const f32x4*>(b1v + mt * 16);
                i32x4 accA = __builtin_amdgcn_mfma_i32_16x16x64_i8(f1, xDA, z, 0, 0, 0);
                accA = __builtin_amdgcn_mfma_i32_16x16x64_i8(f0, xSA, accA, 0, 0, 0);
                i32x4 accB = __builtin_amdgcn_mfma_i32_16x16x64_i8(f1, xDB, z, 0, 0, 0);
                accB = __builtin_amdgcn_mfma_i32_16x16x64_i8(f0, xSB, accB, 0, 0, 0);
                #pragma unroll
                for (int pr = 0; pr < 2; ++pr) {
                    const int r = pr * 2;
                    float hA0 = fmaxf(fmaf((float)accA[r],     sTot, bb[r]),     0.f);
                    float hA1 = fmaxf(fmaf((float)accA[r + 1], sTot, bb[r + 1]), 0.f);
                    __hip_bfloat162 pkA = __float22bfloat162_rn(make_float2(hA0, hA1));
                    reinterpret_cast<unsigned*>(&pA)[half * 2 + pr] = *reinterpret_cast<unsigned*>(&pkA);
                    float hB0 = fmaxf(fmaf((float)accB[r],     sTot, bb[r]),     0.f);
                    float hB1 = fmaxf(fmaf((float)accB[r + 1], sTot, bb[r + 1]), 0.f);
                    __hip_bfloat162 pkB = __float22bfloat162_rn(make_float2(hB0, hB1));
                    reinterpret_cast<unsigned*>(&pB)[half * 2 + pr] = *reinterpret_cast<unsigned*>(&pkB);
                }
            }
            const s16x8 w2r = wf2[ks2 * 64];   // shared by A and B
            oA = __builtin_amdgcn_mfma_f32_16x16x32_bf16(w2r, pA, oA, 0, 0, 0);
            oB = __builtin_amdgcn_mfma_f32_16x16x32_bf16(w2r, pB, oB, 0, 0, 0);
        }
        if (lane < 16) {
            const int eoA = tl * 32 + lane;
            if (eoA < E)
                *reinterpret_cast<float2*>(out + (size_t)eoA * 2) = make_float2(oA[0], oA[1]);
            const int eoB = eoA + 16;
            if (eoB < E)
                *reinterpret_cast<float2*>(out + (size_t)eoB * 2) = make_float2(oB[0], oB[1]);
        }
    };

    // ---- depth-2 pipeline, statically-named sets, no in-loop barrier ----
    int sA0, dA0, sB0, dB0, sA1, dA1, sB1, dB1;
    i32x4 xSA0, xDA0, xSB0, xDB0, xSA1, xDA1, xSB1, xDB1;

    LOADIDX(tile, sA0, dA0, sB0, dB0);
    GATHER(sA0, dA0, sB0, dB0, xSA0, xDA0, xSB0, xDB0);
    LOADIDX(tile + stride, sA1, dA1, sB1, dB1);

    while (true) {
        GATHER(sA1, dA1, sB1, dB1, xSA1, xDA1, xSB1, xDB1);
        LOADIDX(tile + 2 * stride, sA0, dA0, sB0, dB0);
        COMPUTE(tile, xSA0, xDA0, xSB0, xDB0);
        tile += stride;
        if (tile >= nTiles32) break;

        GATHER(sA0, dA0, sB0, dB0, xSA0, xDA0, xSB0, xDB0);
        LOADIDX(tile + 2 * stride, sA1, dA1, sB1, dB1);
        COMPUTE(tile, xSA1, xDA1, xSB1, xDB1);
        tile += stride;
        if (tile >= nTiles32) break;
    }
}

// ---- fallback (ws too small; correct but slow) ----
__global__ void edge_mlp_naive(const float* __restrict__ h, const int* __restrict__ eidx,
                               const float* __restrict__ W1, const float* __restrict__ b1,
                               const float* __restrict__ W2, const float* __restrict__ b2,
                               float* __restrict__ out, int E) {
    const int e = blockIdx.x * 256 + threadIdx.x;
    if (e >= E) return;
    const float* hs = h + (size_t)eidx[e] * EMB;
    const float* hd = h + (size_t)eidx[E + e] * EMB;
    float o0 = b2[0], o1 = b2[1];
    for (int j = 0; j < HID; ++j) {
        float a = b1[j];
        for (int k = 0; k < EMB; ++k)
            a += hs[k] * W1[(size_t)k * HID + j] + hd[k] * W1[(size_t)(k + EMB) * HID + j];
        a = fmaxf(a, 0.f);
        o0 = fmaf(a, W2[j * 2 + 0], o0);
        o1 = fmaf(a, W2[j * 2 + 1], o1);
    }
    out[(size_t)e * 2 + 0] = o0;
    out[(size_t)e * 2 + 1] = o1;
}

extern "C" void kernel_launch(void* const* d_in, const int* in_sizes, int n_in,
                              void* d_out, int out_size, void* d_ws, size_t ws_size,
                              hipStream_t stream)
{
    const float* h  = (const float*)d_in[0];
    const int*   ei = (const int*)d_in[1];
    const float* W1 = (const float*)d_in[2];
    const float* b1 = (const float*)d_in[3];
    const float* W2 = (const float*)d_in[4];
    const float* b2 = (const float*)d_in[5];
    float* out = (float*)d_out;

    const int nNodes   = in_sizes[0] / EMB;
    const int E        = in_sizes[1] / 2;
    const int nTiles32 = (E + 31) / 32;
    const int total    = nNodes * EMB;

    const size_t hq_off = 0;
    const size_t sw_off = (size_t)total;
    const size_t hm_off = sw_off + 4;
    const size_t w1_off = (hm_off + 4 + 15) & ~(size_t)15;
    const size_t w2_off = w1_off + 16384;
    const size_t need   = w2_off + 2048 * 2;

    if (ws_size >= need) {
        char*  ws  = (char*)d_ws;
        char*  hq  = ws + hq_off;
        unsigned* swb = (unsigned*)(ws + sw_off);
        unsigned* hmb = (unsigned*)(ws + hm_off);
        char*  w1q = ws + w1_off;
        unsigned short* w2t = (unsigned short*)(ws + w2_off);

        hipMemsetAsync(swb, 0, 8, stream);   // clears swb and hmb
        hipLaunchKernelGGL(w1max_kernel, dim3(16), dim3(256), 0, stream, W1, swb);
        hipLaunchKernelGGL(hmax_kernel, dim3(2048), dim3(256), 0, stream,
                           h, hmb, total / 4);
        hipLaunchKernelGGL(quant_h_g, dim3((total / 16 + 255) / 256), dim3(256), 0,
                           stream, h, hmb, hq, total / 16);
        hipLaunchKernelGGL(pack_tabs_i8, dim3(72), dim3(256), 0, stream,
                           W1, W2, swb, w1q, w2t);
        hipLaunchKernelGGL(edge_mlp_i8v5, dim3(1792), dim3(256), 0, stream,
                           hq, swb, hmb, w1q, w2t, ei, b1, b2, out, E, nTiles32);
    } else {
        hipLaunchKernelGGL(edge_mlp_naive, dim3((E + 255) / 256), dim3(256), 0, stream,
                           h, ei, W1, b1, W2, b2, out, E);
    }
}

// Round 23
// 74.026 us; speedup vs baseline: 1.2287x; 1.2259x over previous
//
#include <hip/hip_runtime.h>
#include <hip/hip_bf16.h>
#include <cstdint>

// EdgeMLP R20 = R19 main (32-edge tiles, depth-2, validated 50.4us) +
// per-64-node-group scales (R14-validated, absmax 1.17e-2) computed in a
// FUSED single-pass quant kernel -> no global hmax dispatch, h read once.
// Prep = memset + w1max + quant_fused + pack (4 small dispatches).
// ws: [hq: nNodes*64 i8][scf: nG64 f32 folded][swbits u32][w1q 16K i8][w2tab 2048 bf16]

constexpr int EMB = 64;
constexpr int HID = 128;

typedef int   i32x4 __attribute__((ext_vector_type(4)));
typedef short s16x8 __attribute__((ext_vector_type(8)));
typedef float f32x4 __attribute__((ext_vector_type(4)));

__device__ __forceinline__ unsigned short f2bf(float x) {
    unsigned u = __float_as_uint(x);
    u = (u + 0x7fffu + ((u >> 16) & 1u)) >> 16;   // RNE
    return (unsigned short)u;
}

// ---- prep A: global max|W1| (64 atomics total) ----
__global__ void w1max_kernel(const float* __restrict__ W1, unsigned* __restrict__ swbits) {
    const int i = blockIdx.x * 256 + threadIdx.x;   // grid 16
    float4 v = *reinterpret_cast<const float4*>(W1 + (size_t)i * 4);
    float m = fmaxf(fmaxf(fabsf(v.x), fabsf(v.y)), fmaxf(fabsf(v.z), fabsf(v.w)));
    #pragma unroll
    for (int off = 1; off < 64; off <<= 1) m = fmaxf(m, __shfl_xor(m, off, 64));
    if ((threadIdx.x & 63) == 0) atomicMax(swbits, __float_as_uint(m));
}

// ---- prep B: fused per-64-node-group max + quantize (single pass over h);
//      writes scf pre-folded with the W1 scale ----
__global__ void quant_h_fused(const float* __restrict__ h, const unsigned* __restrict__ swb,
                              float* __restrict__ scf, char* __restrict__ hq, int total) {
    __shared__ float red[4];
    const int g = blockIdx.x, t = threadIdx.x;
    const size_t base = (size_t)g * 4096 + (size_t)t * 16;
    const bool full = (base < (size_t)total);   // 16 | total
    float4 v[4];
    float m = 0.f;
    if (full) {
        #pragma unroll
        for (int q = 0; q < 4; ++q) {
            v[q] = *reinterpret_cast<const float4*>(h + base + q * 4);
            m = fmaxf(m, fmaxf(fmaxf(fabsf(v[q].x), fabsf(v[q].y)),
                               fmaxf(fabsf(v[q].z), fabsf(v[q].w))));
        }
    }
    #pragma unroll
    for (int off = 1; off < 64; off <<= 1) m = fmaxf(m, __shfl_xor(m, off, 64));
    if ((t & 63) == 0) red[t >> 6] = m;
    __syncthreads();
    const float gmax = fmaxf(fmaxf(red[0], red[1]), fmaxf(red[2], red[3]));
    const float scale = fmaxf(gmax / 127.f, 1e-20f);
    if (t == 0) {
        const float swv = __uint_as_float(swb[0]) / 127.f;   // sw = max|W1|/127
        scf[g] = scale * swv;                                // folded dequant scale
    }
    if (!full) return;
    const float inv = 1.0f / scale;
    unsigned w[4];
    #pragma unroll
    for (int q = 0; q < 4; ++q) {
        int a = max(-127, min(127, __float2int_rn(v[q].x * inv)));
        int b = max(-127, min(127, __float2int_rn(v[q].y * inv)));
        int c = max(-127, min(127, __float2int_rn(v[q].z * inv)));
        int d = max(-127, min(127, __float2int_rn(v[q].w * inv)));
        w[q] = (a & 255) | ((b & 255) << 8) | ((c & 255) << 16) | ((unsigned)(d & 255) << 24);
    }
    *reinterpret_cast<uint4*>(hq + base) = make_uint4(w[0], w[1], w[2], w[3]);
}

// ---- prep C: W1 i8 fragments + W2 bf16 fragments (validated layouts) ----
__global__ void pack_tabs_i8(const float* __restrict__ W1, const float* __restrict__ W2,
                             const unsigned* __restrict__ swb,
                             char* __restrict__ w1q, unsigned short* __restrict__ w2t) {
    const int i = blockIdx.x * blockDim.x + threadIdx.x;
    if (i < 16384) {
        const int j = i & 15, lane = (i >> 4) & 63, half = (i >> 10) & 1, mt = i >> 11;
        const int k = half * 64 + (lane >> 4) * 16 + j;
        const int n = mt * 16 + (lane & 15);
        const float inv = 127.f / fmaxf(__uint_as_float(swb[0]), 1e-18f);
        w1q[i] = (char)max(-127, min(127, __float2int_rn(W1[(size_t)k * HID + n] * inv)));
    } else if (i < 16384 + 2048) {
        const int q = i - 16384;
        const int j = q & 7, lane = (q >> 3) & 63, ks = q >> 9;
        const int tc = lane & 15, bq = lane >> 4;
        const int mt = ks * 2 + (j >> 2), r = j & 3;
        w2t[q] = (tc < 2) ? f2bf(W2[(mt * 16 + bq * 4 + r) * 2 + tc]) : (unsigned short)0;
    }
}

// ---- main: 32-edge tiles, depth-2, per-group scales ----
__global__ __launch_bounds__(256, 2)
void edge_mlp_i8v6(const char* __restrict__ hq,
                   const float* __restrict__ scf,
                   const char* __restrict__ w1q,
                   const unsigned short* __restrict__ w2t,
                   const int* __restrict__ eidx,
                   const float* __restrict__ b1,
                   const float* __restrict__ b2,
                   float* __restrict__ out, int E, int nTiles32)
{
    __shared__ uint4 w1s[1024];   // 16 KB i8 W1 fragments
    __shared__ uint4 w2s[256];    // 4 KB  W2 bf16 fragments
    __shared__ float b1s[128];    // 512 B
    {
        const uint4* src = reinterpret_cast<const uint4*>(w1q);
        #pragma unroll
        for (int r = 0; r < 4; ++r)
            w1s[r * 256 + threadIdx.x] = src[r * 256 + threadIdx.x];
        w2s[threadIdx.x] = *(reinterpret_cast<const uint4*>(w2t) + threadIdx.x);
        if (threadIdx.x < 128) b1s[threadIdx.x] = b1[threadIdx.x];
    }
    __syncthreads();

    const int t = threadIdx.x, wid = t >> 6, lane = t & 63;
    const int tc = lane & 15, bq = lane >> 4;
    const i32x4* wq  = reinterpret_cast<const i32x4*>(w1s) + lane;  // + (mt*2+half)*64
    const s16x8* wf2 = reinterpret_cast<const s16x8*>(w2s) + lane;  // + ks2*64
    const float* b1v = b1s + bq * 4;                                // + mt*16

    const float a20 = (bq == 0) ? b2[0] : 0.f;
    const float a21 = (bq == 0) ? b2[1] : 0.f;

    const int stride = gridDim.x * 4;
    int tile = blockIdx.x * 4 + wid;
    if (tile >= nTiles32) return;

    auto LOADIDX = [&](int tl, int& sA, int& dA, int& sB, int& dB) {
        if (tl < nTiles32) {
            const int base = tl * 32;
            const int eA = min(base + tc, E - 1);
            const int eB = min(base + 16 + tc, E - 1);
            sA = eidx[eA]; dA = eidx[E + eA];
            sB = eidx[eB]; dB = eidx[E + eB];
        } else { sA = 0; dA = 0; sB = 0; dB = 0; }
    };
    auto GATHER = [&](int sA, int dA, int sB, int dB,
                      i32x4& xSA, i32x4& xDA, i32x4& xSB, i32x4& xDB,
                      float& fSA, float& fDA, float& fSB, float& fDB) {
        xSA = *reinterpret_cast<const i32x4*>(hq + (size_t)sA * EMB + bq * 16);
        xDA = *reinterpret_cast<const i32x4*>(hq + (size_t)dA * EMB + bq * 16);
        xSB = *reinterpret_cast<const i32x4*>(hq + (size_t)sB * EMB + bq * 16);
        xDB = *reinterpret_cast<const i32x4*>(hq + (size_t)dB * EMB + bq * 16);
        fSA = scf[sA >> 6]; fDA = scf[dA >> 6];
        fSB = scf[sB >> 6]; fDB = scf[dB >> 6];
    };
    auto COMPUTE = [&](int tl, i32x4 xSA, i32x4 xDA, i32x4 xSB, i32x4 xDB,
                       float fSA, float fDA, float fSB, float fDB) {
        const i32x4 z = {0, 0, 0, 0};
        f32x4 oA = {a20, a21, 0.f, 0.f};
        f32x4 oB = {a20, a21, 0.f, 0.f};
        #pragma unroll
        for (int ks2 = 0; ks2 < 4; ++ks2) {
            s16x8 pA, pB;
            #pragma unroll
            for (int half = 0; half < 2; ++half) {
                const int mt = ks2 * 2 + half;
                const i32x4 f0 = wq[(mt * 2 + 0) * 64];   // shared by A and B
                const i32x4 f1 = wq[(mt * 2 + 1) * 64];
                const f32x4 bb = *reinterpret_cast<const f32x4*>(b1v + mt * 16);
                const i32x4 aSA = __builtin_amdgcn_mfma_i32_16x16x64_i8(f0, xSA, z, 0, 0, 0);
                const i32x4 aDA = __builtin_amdgcn_mfma_i32_16x16x64_i8(f1, xDA, z, 0, 0, 0);
                const i32x4 aSB = __builtin_amdgcn_mfma_i32_16x16x64_i8(f0, xSB, z, 0, 0, 0);
                const i32x4 aDB = __builtin_amdgcn_mfma_i32_16x16x64_i8(f1, xDB, z, 0, 0, 0);
                #pragma unroll
                for (int pr = 0; pr < 2; ++pr) {
                    const int r = pr * 2;
                    float hA0 = fmaxf(fmaf((float)aSA[r],     fSA, fmaf((float)aDA[r],     fDA, bb[r]    )), 0.f);
                    float hA1 = fmaxf(fmaf((float)aSA[r + 1], fSA, fmaf((float)aDA[r + 1], fDA, bb[r + 1])), 0.f);
                    __hip_bfloat162 pkA = __float22bfloat162_rn(make_float2(hA0, hA1));
                    reinterpret_cast<unsigned*>(&pA)[half * 2 + pr] = *reinterpret_cast<unsigned*>(&pkA);
                    float hB0 = fmaxf(fmaf((float)aSB[r],     fSB, fmaf((float)aDB[r],     fDB, bb[r]    )), 0.f);
                    float hB1 = fmaxf(fmaf((float)aSB[r + 1], fSB, fmaf((float)aDB[r + 1], fDB, bb[r + 1])), 0.f);
                    __hip_bfloat162 pkB = __float22bfloat162_rn(make_float2(hB0, hB1));
                    reinterpret_cast<unsigned*>(&pB)[half * 2 + pr] = *reinterpret_cast<unsigned*>(&pkB);
                }
            }
            const s16x8 w2r = wf2[ks2 * 64];   // shared by A and B
            oA = __builtin_amdgcn_mfma_f32_16x16x32_bf16(w2r, pA, oA, 0, 0, 0);
            oB = __builtin_amdgcn_mfma_f32_16x16x32_bf16(w2r, pB, oB, 0, 0, 0);
        }
        if (lane < 16) {
            const int eoA = tl * 32 + lane;
            if (eoA < E)
                *reinterpret_cast<float2*>(out + (size_t)eoA * 2) = make_float2(oA[0], oA[1]);
            const int eoB = eoA + 16;
            if (eoB < E)
                *reinterpret_cast<float2*>(out + (size_t)eoB * 2) = make_float2(oB[0], oB[1]);
        }
    };

    // ---- depth-2 pipeline, statically-named sets, no in-loop barrier ----
    int sA0, dA0, sB0, dB0, sA1, dA1, sB1, dB1;
    i32x4 xSA0, xDA0, xSB0, xDB0, xSA1, xDA1, xSB1, xDB1;
    float fSA0, fDA0, fSB0, fDB0, fSA1, fDA1, fSB1, fDB1;

    LOADIDX(tile, sA0, dA0, sB0, dB0);
    GATHER(sA0, dA0, sB0, dB0, xSA0, xDA0, xSB0, xDB0, fSA0, fDA0, fSB0, fDB0);
    LOADIDX(tile + stride, sA1, dA1, sB1, dB1);

    while (true) {
        GATHER(sA1, dA1, sB1, dB1, xSA1, xDA1, xSB1, xDB1, fSA1, fDA1, fSB1, fDB1);
        LOADIDX(tile + 2 * stride, sA0, dA0, sB0, dB0);
        COMPUTE(tile, xSA0, xDA0, xSB0, xDB0, fSA0, fDA0, fSB0, fDB0);
        tile += stride;
        if (tile >= nTiles32) break;

        GATHER(sA0, dA0, sB0, dB0, xSA0, xDA0, xSB0, xDB0, fSA0, fDA0, fSB0, fDB0);
        LOADIDX(tile + 2 * stride, sA1, dA1, sB1, dB1);
        COMPUTE(tile, xSA1, xDA1, xSB1, xDB1, fSA1, fDA1, fSB1, fDB1);
        tile += stride;
        if (tile >= nTiles32) break;
    }
}

// ---- fallback (ws too small; correct but slow) ----
__global__ void edge_mlp_naive(const float* __restrict__ h, const int* __restrict__ eidx,
                               const float* __restrict__ W1, const float* __restrict__ b1,
                               const float* __restrict__ W2, const float* __restrict__ b2,
                               float* __restrict__ out, int E) {
    const int e = blockIdx.x * 256 + threadIdx.x;
    if (e >= E) return;
    const float* hs = h + (size_t)eidx[e] * EMB;
    const float* hd = h + (size_t)eidx[E + e] * EMB;
    float o0 = b2[0], o1 = b2[1];
    for (int j = 0; j < HID; ++j) {
        float a = b1[j];
        for (int k = 0; k < EMB; ++k)
            a += hs[k] * W1[(size_t)k * HID + j] + hd[k] * W1[(size_t)(k + EMB) * HID + j];
        a = fmaxf(a, 0.f);
        o0 = fmaf(a, W2[j * 2 + 0], o0);
        o1 = fmaf(a, W2[j * 2 + 1], o1);
    }
    out[(size_t)e * 2 + 0] = o0;
    out[(size_t)e * 2 + 1] = o1;
}

extern "C" void kernel_launch(void* const* d_in, const int* in_sizes, int n_in,
                              void* d_out, int out_size, void* d_ws, size_t ws_size,
                              hipStream_t stream)
{
    const float* h  = (const float*)d_in[0];
    const int*   ei = (const int*)d_in[1];
    const float* W1 = (const float*)d_in[2];
    const float* b1 = (const float*)d_in[3];
    const float* W2 = (const float*)d_in[4];
    const float* b2 = (const float*)d_in[5];
    float* out = (float*)d_out;

    const int nNodes   = in_sizes[0] / EMB;
    const int E        = in_sizes[1] / 2;
    const int nTiles32 = (E + 31) / 32;
    const int nG64     = (nNodes + 63) >> 6;
    const int total    = nNodes * EMB;

    const size_t hq_off = 0;
    const size_t sc_off = (size_t)total;
    const size_t sw_off = sc_off + (size_t)nG64 * 4;
    const size_t w1_off = (sw_off + 4 + 15) & ~(size_t)15;
    const size_t w2_off = w1_off + 16384;
    const size_t need   = w2_off + 2048 * 2;

    if (ws_size >= need) {
        char*  ws  = (char*)d_ws;
        char*  hq  = ws + hq_off;
        float* scf = (float*)(ws + sc_off);
        unsigned* swb = (unsigned*)(ws + sw_off);
        char*  w1q = ws + w1_off;
        unsigned short* w2t = (unsigned short*)(ws + w2_off);

        hipMemsetAsync(swb, 0, 4, stream);
        hipLaunchKernelGGL(w1max_kernel, dim3(16), dim3(256), 0, stream, W1, swb);
        hipLaunchKernelGGL(quant_h_fused, dim3(nG64), dim3(256), 0, stream,
                           h, swb, scf, hq, total);
        hipLaunchKernelGGL(pack_tabs_i8, dim3(72), dim3(256), 0, stream,
                           W1, W2, swb, w1q, w2t);
        hipLaunchKernelGGL(edge_mlp_i8v6, dim3(1792), dim3(256), 0, stream,
                           hq, scf, w1q, w2t, ei, b1, b2, out, E, nTiles32);
    } else {
        hipLaunchKernelGGL(edge_mlp_naive, dim3((E + 255) / 256), dim3(256), 0, stream,
                           h, ei, W1, b1, W2, b2, out, E);
    }
}

// Round 25
// 61.931 us; speedup vs baseline: 1.4686x; 1.1953x over previous
//
#include <hip/hip_runtime.h>
#include <hip/hip_bf16.h>
#include <cstdint>

// EdgeMLP R25 = R19 main kernel VERBATIM (32-edge tiles, depth-2, global scale,
// validated 50.4us / absmax 1.66e-2) + 3-dispatch atomic-free prep:
//   1) maxes_kernel: blockmax of |h| (2048 blocks, grid-stride) and |W1|
//      (blocks 0-15). No atomics, no memset (every slot written).
//   2) quant_pack: quant blocks re-reduce bmh in-block then quantize h;
//      pack blocks re-reduce bmw then pack W1 i8 / W2 bf16 fragment tables;
//      writes hmb/swb scalars for the main kernel.
//   3) main.
// ws: [hq][bmh 2048 f32][bmw 16 f32][hmb u32][swb u32][w1q 16K i8][w2t 2048 bf16]

constexpr int EMB = 64;
constexpr int HID = 128;
constexpr int MAX_GRID = 2048;

typedef int   i32x4 __attribute__((ext_vector_type(4)));
typedef short s16x8 __attribute__((ext_vector_type(8)));
typedef float f32x4 __attribute__((ext_vector_type(4)));

__device__ __forceinline__ unsigned short f2bf(float x) {
    unsigned u = __float_as_uint(x);
    u = (u + 0x7fffu + ((u >> 16) & 1u)) >> 16;   // RNE
    return (unsigned short)u;
}

__device__ __forceinline__ float blockReduceMax(float m, float* red) {
    #pragma unroll
    for (int off = 1; off < 64; off <<= 1) m = fmaxf(m, __shfl_xor(m, off, 64));
    if ((threadIdx.x & 63) == 0) red[threadIdx.x >> 6] = m;
    __syncthreads();
    return fmaxf(fmaxf(red[0], red[1]), fmaxf(red[2], red[3]));
}

// ---- prep 1: block maxes of |h| (all blocks) and |W1| (blocks 0-15) ----
__global__ void maxes_kernel(const float* __restrict__ h, const float* __restrict__ W1,
                             float* __restrict__ bmh, float* __restrict__ bmw, int n4) {
    __shared__ float red[4];
    float m = 0.f;
    for (int i = blockIdx.x * blockDim.x + threadIdx.x; i < n4;
         i += gridDim.x * blockDim.x) {
        float4 v = *reinterpret_cast<const float4*>(h + (size_t)i * 4);
        m = fmaxf(m, fmaxf(fmaxf(fabsf(v.x), fabsf(v.y)), fmaxf(fabsf(v.z), fabsf(v.w))));
    }
    const float hb = blockReduceMax(m, red);
    if (threadIdx.x == 0) bmh[blockIdx.x] = hb;

    if (blockIdx.x < 16) {   // W1: 4096 float4 over 16 blocks x 256 thr
        __syncthreads();
        float4 v = *reinterpret_cast<const float4*>(
            W1 + (size_t)(blockIdx.x * 256 + threadIdx.x) * 4);
        float w = fmaxf(fmaxf(fabsf(v.x), fabsf(v.y)), fmaxf(fabsf(v.z), fabsf(v.w)));
        const float wb = blockReduceMax(w, red);
        if (threadIdx.x == 0) bmw[blockIdx.x] = wb;
    }
}

// ---- prep 2: fused quantize-h + pack-tables (single dispatch) ----
__global__ void quant_pack(const float* __restrict__ h,
                           const float* __restrict__ W1, const float* __restrict__ W2,
                           const float* __restrict__ bmh, const float* __restrict__ bmw,
                           unsigned* __restrict__ hmb, unsigned* __restrict__ swb,
                           char* __restrict__ hq, char* __restrict__ w1q,
                           unsigned short* __restrict__ w2t, int n16, int nQB) {
    __shared__ float red[4];
    if ((int)blockIdx.x < nQB) {
        // re-reduce bmh (2048 entries)
        float m = 0.f;
        for (int i = threadIdx.x; i < MAX_GRID; i += 256) m = fmaxf(m, bmh[i]);
        const float gmax = blockReduceMax(m, red);
        const float inv = 127.f / fmaxf(gmax, 1e-18f);
        if (blockIdx.x == 0 && threadIdx.x == 0) hmb[0] = __float_as_uint(gmax);

        const int i = blockIdx.x * 256 + threadIdx.x;
        if (i < n16) {
            const float* p = h + (size_t)i * 16;
            unsigned w[4];
            #pragma unroll
            for (int q = 0; q < 4; ++q) {
                float4 v = *reinterpret_cast<const float4*>(p + q * 4);
                int a = max(-127, min(127, __float2int_rn(v.x * inv)));
                int b = max(-127, min(127, __float2int_rn(v.y * inv)));
                int c = max(-127, min(127, __float2int_rn(v.z * inv)));
                int d = max(-127, min(127, __float2int_rn(v.w * inv)));
                w[q] = (a & 255) | ((b & 255) << 8) | ((c & 255) << 16)
                       | ((unsigned)(d & 255) << 24);
            }
            *reinterpret_cast<uint4*>(hq + (size_t)i * 16) =
                make_uint4(w[0], w[1], w[2], w[3]);
        }
    } else {
        // re-reduce bmw (16 entries)
        float m = (threadIdx.x < 16) ? bmw[threadIdx.x] : 0.f;
        const float swmax = blockReduceMax(m, red);
        const float inv = 127.f / fmaxf(swmax, 1e-18f);
        if ((int)blockIdx.x == nQB && threadIdx.x == 0)
            swb[0] = __float_as_uint(swmax);

        const int i = ((int)blockIdx.x - nQB) * 256 + threadIdx.x;
        if (i < 16384) {
            const int j = i & 15, lane = (i >> 4) & 63, half = (i >> 10) & 1, mt = i >> 11;
            const int k = half * 64 + (lane >> 4) * 16 + j;
            const int n = mt * 16 + (lane & 15);
            w1q[i] = (char)max(-127, min(127,
                         __float2int_rn(W1[(size_t)k * HID + n] * inv)));
        } else if (i < 16384 + 2048) {
            const int q = i - 16384;
            const int j = q & 7, lane = (q >> 3) & 63, ks = q >> 9;
            const int tc = lane & 15, bq = lane >> 4;
            const int mt = ks * 2 + (j >> 2), r = j & 3;
            w2t[q] = (tc < 2) ? f2bf(W2[(mt * 16 + bq * 4 + r) * 2 + tc])
                              : (unsigned short)0;
        }
    }
}

// ---- main: R19's edge_mlp_i8v5 verbatim (validated 50.4us) ----
__global__ __launch_bounds__(256, 2)
void edge_mlp_i8v5(const char* __restrict__ hq,
                   const unsigned* __restrict__ swb,
                   const unsigned* __restrict__ hmb,
                   const char* __restrict__ w1q,
                   const unsigned short* __restrict__ w2t,
                   const int* __restrict__ eidx,
                   const float* __restrict__ b1,
                   const float* __restrict__ b2,
                   float* __restrict__ out, int E, int nTiles32)
{
    __shared__ uint4 w1s[1024];   // 16 KB i8 W1 fragments
    __shared__ uint4 w2s[256];    // 4 KB  W2 bf16 fragments
    __shared__ float b1s[128];    // 512 B
    {
        const uint4* src = reinterpret_cast<const uint4*>(w1q);
        #pragma unroll
        for (int r = 0; r < 4; ++r)
            w1s[r * 256 + threadIdx.x] = src[r * 256 + threadIdx.x];
        w2s[threadIdx.x] = *(reinterpret_cast<const uint4*>(w2t) + threadIdx.x);
        if (threadIdx.x < 128) b1s[threadIdx.x] = b1[threadIdx.x];
    }
    __syncthreads();

    const float sTot = __uint_as_float(hmb[0]) * __uint_as_float(swb[0])
                       * (1.0f / (127.f * 127.f));

    const int t = threadIdx.x, wid = t >> 6, lane = t & 63;
    const int tc = lane & 15, bq = lane >> 4;
    const i32x4* wq  = reinterpret_cast<const i32x4*>(w1s) + lane;  // + (mt*2+half)*64
    const s16x8* wf2 = reinterpret_cast<const s16x8*>(w2s) + lane;  // + ks2*64
    const float* b1v = b1s + bq * 4;                                // + mt*16

    const float a20 = (bq == 0) ? b2[0] : 0.f;
    const float a21 = (bq == 0) ? b2[1] : 0.f;

    const int stride = gridDim.x * 4;
    int tile = blockIdx.x * 4 + wid;
    if (tile >= nTiles32) return;

    auto LOADIDX = [&](int tl, int& sA, int& dA, int& sB, int& dB) {
        if (tl < nTiles32) {
            const int base = tl * 32;
            const int eA = min(base + tc, E - 1);
            const int eB = min(base + 16 + tc, E - 1);
            sA = eidx[eA]; dA = eidx[E + eA];
            sB = eidx[eB]; dB = eidx[E + eB];
        } else { sA = 0; dA = 0; sB = 0; dB = 0; }
    };
    auto GATHER = [&](int sA, int dA, int sB, int dB,
                      i32x4& xSA, i32x4& xDA, i32x4& xSB, i32x4& xDB) {
        xSA = *reinterpret_cast<const i32x4*>(hq + (size_t)sA * EMB + bq * 16);
        xDA = *reinterpret_cast<const i32x4*>(hq + (size_t)dA * EMB + bq * 16);
        xSB = *reinterpret_cast<const i32x4*>(hq + (size_t)sB * EMB + bq * 16);
        xDB = *reinterpret_cast<const i32x4*>(hq + (size_t)dB * EMB + bq * 16);
    };
    auto COMPUTE = [&](int tl, i32x4 xSA, i32x4 xDA, i32x4 xSB, i32x4 xDB) {
        const i32x4 z = {0, 0, 0, 0};
        f32x4 oA = {a20, a21, 0.f, 0.f};
        f32x4 oB = {a20, a21, 0.f, 0.f};
        #pragma unroll
        for (int ks2 = 0; ks2 < 4; ++ks2) {
            s16x8 pA, pB;
            #pragma unroll
            for (int half = 0; half < 2; ++half) {
                const int mt = ks2 * 2 + half;
                const i32x4 f0 = wq[(mt * 2 + 0) * 64];   // shared by A and B
                const i32x4 f1 = wq[(mt * 2 + 1) * 64];
                const f32x4 bb = *reinterpret_cast<const f32x4*>(b1v + mt * 16);
                i32x4 accA = __builtin_amdgcn_mfma_i32_16x16x64_i8(f1, xDA, z, 0, 0, 0);
                accA = __builtin_amdgcn_mfma_i32_16x16x64_i8(f0, xSA, accA, 0, 0, 0);
                i32x4 accB = __builtin_amdgcn_mfma_i32_16x16x64_i8(f1, xDB, z, 0, 0, 0);
                accB = __builtin_amdgcn_mfma_i32_16x16x64_i8(f0, xSB, accB, 0, 0, 0);
                #pragma unroll
                for (int pr = 0; pr < 2; ++pr) {
                    const int r = pr * 2;
                    float hA0 = fmaxf(fmaf((float)accA[r],     sTot, bb[r]),     0.f);
                    float hA1 = fmaxf(fmaf((float)accA[r + 1], sTot, bb[r + 1]), 0.f);
                    __hip_bfloat162 pkA = __float22bfloat162_rn(make_float2(hA0, hA1));
                    reinterpret_cast<unsigned*>(&pA)[half * 2 + pr] = *reinterpret_cast<unsigned*>(&pkA);
                    float hB0 = fmaxf(fmaf((float)accB[r],     sTot, bb[r]),     0.f);
                    float hB1 = fmaxf(fmaf((float)accB[r + 1], sTot, bb[r + 1]), 0.f);
                    __hip_bfloat162 pkB = __float22bfloat162_rn(make_float2(hB0, hB1));
                    reinterpret_cast<unsigned*>(&pB)[half * 2 + pr] = *reinterpret_cast<unsigned*>(&pkB);
                }
            }
            const s16x8 w2r = wf2[ks2 * 64];   // shared by A and B
            oA = __builtin_amdgcn_mfma_f32_16x16x32_bf16(w2r, pA, oA, 0, 0, 0);
            oB = __builtin_amdgcn_mfma_f32_16x16x32_bf16(w2r, pB, oB, 0, 0, 0);
        }
        if (lane < 16) {
            const int eoA = tl * 32 + lane;
            if (eoA < E)
                *reinterpret_cast<float2*>(out + (size_t)eoA * 2) = make_float2(oA[0], oA[1]);
            const int eoB = eoA + 16;
            if (eoB < E)
                *reinterpret_cast<float2*>(out + (size_t)eoB * 2) = make_float2(oB[0], oB[1]);
        }
    };

    // ---- depth-2 pipeline, statically-named sets, no in-loop barrier ----
    int sA0, dA0, sB0, dB0, sA1, dA1, sB1, dB1;
    i32x4 xSA0, xDA0, xSB0, xDB0, xSA1, xDA1, xSB1, xDB1;

    LOADIDX(tile, sA0, dA0, sB0, dB0);
    GATHER(sA0, dA0, sB0, dB0, xSA0, xDA0, xSB0, xDB0);
    LOADIDX(tile + stride, sA1, dA1, sB1, dB1);

    while (true) {
        GATHER(sA1, dA1, sB1, dB1, xSA1, xDA1, xSB1, xDB1);
        LOADIDX(tile + 2 * stride, sA0, dA0, sB0, dB0);
        COMPUTE(tile, xSA0, xDA0, xSB0, xDB0);
        tile += stride;
        if (tile >= nTiles32) break;

        GATHER(sA0, dA0, sB0, dB0, xSA0, xDA0, xSB0, xDB0);
        LOADIDX(tile + 2 * stride, sA1, dA1, sB1, dB1);
        COMPUTE(tile, xSA1, xDA1, xSB1, xDB1);
        tile += stride;
        if (tile >= nTiles32) break;
    }
}

// ---- fallback (ws too small; correct but slow) ----
__global__ void edge_mlp_naive(const float* __restrict__ h, const int* __restrict__ eidx,
                               const float* __restrict__ W1, const float* __restrict__ b1,
                               const float* __restrict__ W2, const float* __restrict__ b2,
                               float* __restrict__ out, int E) {
    const int e = blockIdx.x * 256 + threadIdx.x;
    if (e >= E) return;
    const float* hs = h + (size_t)eidx[e] * EMB;
    const float* hd = h + (size_t)eidx[E + e] * EMB;
    float o0 = b2[0], o1 = b2[1];
    for (int j = 0; j < HID; ++j) {
        float a = b1[j];
        for (int k = 0; k < EMB; ++k)
            a += hs[k] * W1[(size_t)k * HID + j] + hd[k] * W1[(size_t)(k + EMB) * HID + j];
        a = fmaxf(a, 0.f);
        o0 = fmaf(a, W2[j * 2 + 0], o0);
        o1 = fmaf(a, W2[j * 2 + 1], o1);
    }
    out[(size_t)e * 2 + 0] = o0;
    out[(size_t)e * 2 + 1] = o1;
}

extern "C" void kernel_launch(void* const* d_in, const int* in_sizes, int n_in,
                              void* d_out, int out_size, void* d_ws, size_t ws_size,
                              hipStream_t stream)
{
    const float* h  = (const float*)d_in[0];
    const int*   ei = (const int*)d_in[1];
    const float* W1 = (const float*)d_in[2];
    const float* b1 = (const float*)d_in[3];
    const float* W2 = (const float*)d_in[4];
    const float* b2 = (const float*)d_in[5];
    float* out = (float*)d_out;

    const int nNodes   = in_sizes[0] / EMB;
    const int E        = in_sizes[1] / 2;
    const int nTiles32 = (E + 31) / 32;
    const int total    = nNodes * EMB;
    const int n16      = total / 16;
    const int nQB      = (n16 + 255) / 256;

    const size_t hq_off  = 0;
    const size_t bmh_off = (size_t)total;                       // 64 | total
    const size_t bmw_off = bmh_off + (size_t)MAX_GRID * 4;
    const size_t hm_off  = bmw_off + 16 * 4;
    const size_t sw_off  = hm_off + 4;
    const size_t w1_off  = (sw_off + 4 + 15) & ~(size_t)15;
    const size_t w2_off  = w1_off + 16384;
    const size_t need    = w2_off + 2048 * 2;

    if (ws_size >= need) {
        char*     ws  = (char*)d_ws;
        char*     hq  = ws + hq_off;
        float*    bmh = (float*)(ws + bmh_off);
        float*    bmw = (float*)(ws + bmw_off);
        unsigned* hmb = (unsigned*)(ws + hm_off);
        unsigned* swb = (unsigned*)(ws + sw_off);
        char*     w1q = ws + w1_off;
        unsigned short* w2t = (unsigned short*)(ws + w2_off);

        hipLaunchKernelGGL(maxes_kernel, dim3(MAX_GRID), dim3(256), 0, stream,
                           h, W1, bmh, bmw, total / 4);
        hipLaunchKernelGGL(quant_pack, dim3(nQB + 72), dim3(256), 0, stream,
                           h, W1, W2, bmh, bmw, hmb, swb, hq, w1q, w2t, n16, nQB);
        hipLaunchKernelGGL(edge_mlp_i8v5, dim3(1792), dim3(256), 0, stream,
                           hq, swb, hmb, w1q, w2t, ei, b1, b2, out, E, nTiles32);
    } else {
        hipLaunchKernelGGL(edge_mlp_naive, dim3((E + 255) / 256), dim3(256), 0, stream,
                           h, ei, W1, b1, W2, b2, out, E);
    }
}